// Round 1
// baseline (2347.594 us; speedup 1.0000x reference)
//
#include <hip/hip_runtime.h>
#include <cstdint>
#include <cmath>

// Problem constants (match reference)
#define NN 100000   // nodes
#define EE 500000   // edges
// DN=64, DE=64, D=128, TD=64, K_self = 192
#define CAP 64      // incidence-list capacity per node (Poisson(10): P(deg>64) ~ 1e-50)

// ---------------------------------------------------------------------------
// Build per-node incidence lists (replaces f32 scatter-atomics with a gather).
// entry = (e<<1) | side. side=1 -> contribution is feat_dst row e (node is src),
// side=0 -> contribution is feat_src row e (node is dst).
// pos[] doubles as the node degree (== reference cnt).
__global__ __launch_bounds__(256) void k_build(const int* __restrict__ src,
                                               const int* __restrict__ dst,
                                               int* __restrict__ pos,
                                               int* __restrict__ eidx) {
    int e = blockIdx.x * 256 + threadIdx.x;
    if (e >= EE) return;
    int s = src[e], d = dst[e];
    int sl = atomicAdd(&pos[s], 1);
    if (sl < CAP) eidx[(size_t)s * CAP + sl] = (e << 1) | 1;
    int dl = atomicAdd(&pos[d], 1);
    if (dl < CAP) eidx[(size_t)d * CAP + dl] = (e << 1);
}

// ---------------------------------------------------------------------------
// combine_feats: feat_src[e] = [nfeat[src[e]], efeat[e]], feat_dst likewise.
// One float4 per thread per output; grid = EE*32/256 exactly.
__global__ __launch_bounds__(256) void k_combine(const float* __restrict__ nfeat,
                                                 const float* __restrict__ efeat,
                                                 const int* __restrict__ src,
                                                 const int* __restrict__ dst,
                                                 float* __restrict__ outS,
                                                 float* __restrict__ outD) {
    int idx = blockIdx.x * 256 + threadIdx.x;   // over EE*32 float4s
    int e = idx >> 5, c4 = idx & 31;
    size_t o = (size_t)e * 128 + c4 * 4;
    if (c4 < 16) {
        int s = src[e], d = dst[e];
        float4 vs = *(const float4*)(nfeat + (size_t)s * 64 + c4 * 4);
        float4 vd = *(const float4*)(nfeat + (size_t)d * 64 + c4 * 4);
        *(float4*)(outS + o) = vs;
        *(float4*)(outD + o) = vd;
    } else {
        float4 v = *(const float4*)(efeat + (size_t)e * 64 + (c4 - 16) * 4);
        *(float4*)(outS + o) = v;
        *(float4*)(outD + o) = v;
    }
}

// ---------------------------------------------------------------------------
// Aggregation: one wave per node; lane holds 2 of 128 channels in registers.
// mean[n] = (sum of incident rows) / max(deg,1)
__global__ __launch_bounds__(256) void k_agg(const float* __restrict__ featS,
                                             const float* __restrict__ featD,
                                             const int* __restrict__ pos,
                                             const int* __restrict__ eidx,
                                             float* __restrict__ mean) {
    int w = (blockIdx.x * 256 + threadIdx.x) >> 6;   // node id
    int lane = threadIdx.x & 63;
    if (w >= NN) return;
    int d = pos[w];
    int dd = min(d, CAP);
    const int* lst = eidx + (size_t)w * CAP;
    float ax = 0.f, ay = 0.f;
    for (int j = 0; j < dd; ++j) {
        int entry = lst[j];                         // wave-uniform
        const float* base = (entry & 1) ? featD : featS;
        float2 v = *(const float2*)(base + ((size_t)(entry >> 1)) * 128 + lane * 2);
        ax += v.x; ay += v.y;
    }
    float inv = 1.0f / fmaxf((float)d, 1.0f);
    float2 r; r.x = ax * inv; r.y = ay * inv;
    *(float2*)(mean + (size_t)w * 128 + lane * 2) = r;
}

// ---------------------------------------------------------------------------
// neigh_proj = mean @ W_neigh + b_neigh.  Tile: 64 nodes x 128 cols per block,
// 256 threads, each computes 4 rows x 8 cols. K=128 in chunks of 16.
__global__ __launch_bounds__(256) void k_neigh(const float* __restrict__ mean,
                                               const float* __restrict__ W,
                                               const float* __restrict__ bias,
                                               float* __restrict__ outp) {
    __shared__ float Xs[16][68];    // [k][row], stride 68 -> <=2-way bank alias
    __shared__ float Ws[16][128];   // [k][col]
    int tid = threadIdx.x;
    int n0 = blockIdx.x * 64;
    int tx = tid & 15, ty = tid >> 4;
    float acc[4][8];
#pragma unroll
    for (int i = 0; i < 4; ++i)
#pragma unroll
        for (int j = 0; j < 8; ++j) acc[i][j] = 0.f;

    for (int ch = 0; ch < 8; ++ch) {
        int k0 = ch * 16;
        {   // stage W chunk: 512 float4, 2 per thread
            int v = tid;
#pragma unroll
            for (int r = 0; r < 2; ++r, v += 256) {
                int kk = v >> 5, c4 = v & 31;
                *(float4*)&Ws[kk][c4 * 4] =
                    *(const float4*)(W + (size_t)(k0 + kk) * 128 + c4 * 4);
            }
        }
        {   // stage X chunk transposed: 256 float4, 1 per thread
            int row = tid >> 2, q = tid & 3;
            int n = min(n0 + row, NN - 1);
            float4 x = *(const float4*)(mean + (size_t)n * 128 + k0 + q * 4);
            Xs[q * 4 + 0][row] = x.x; Xs[q * 4 + 1][row] = x.y;
            Xs[q * 4 + 2][row] = x.z; Xs[q * 4 + 3][row] = x.w;
        }
        __syncthreads();
#pragma unroll
        for (int kk = 0; kk < 16; ++kk) {
            float4 a  = *(const float4*)&Xs[kk][4 * ty];
            float4 b0 = *(const float4*)&Ws[kk][4 * tx];
            float4 b1 = *(const float4*)&Ws[kk][64 + 4 * tx];
            float av[4] = {a.x, a.y, a.z, a.w};
            float bv[8] = {b0.x, b0.y, b0.z, b0.w, b1.x, b1.y, b1.z, b1.w};
#pragma unroll
            for (int i = 0; i < 4; ++i)
#pragma unroll
                for (int j = 0; j < 8; ++j)
                    acc[i][j] = fmaf(av[i], bv[j], acc[i][j]);
        }
        __syncthreads();
    }
    float4 bb0 = *(const float4*)(bias + 4 * tx);
    float4 bb1 = *(const float4*)(bias + 64 + 4 * tx);
#pragma unroll
    for (int i = 0; i < 4; ++i) {
        int n = n0 + 4 * ty + i;
        if (n < NN) {
            float4 r0, r1;
            r0.x = acc[i][0] + bb0.x; r0.y = acc[i][1] + bb0.y;
            r0.z = acc[i][2] + bb0.z; r0.w = acc[i][3] + bb0.w;
            r1.x = acc[i][4] + bb1.x; r1.y = acc[i][5] + bb1.y;
            r1.z = acc[i][6] + bb1.z; r1.w = acc[i][7] + bb1.w;
            *(float4*)(outp + (size_t)n * 128 + 4 * tx) = r0;
            *(float4*)(outp + (size_t)n * 128 + 64 + 4 * tx) = r1;
        }
    }
}

// ---------------------------------------------------------------------------
// Edge update: rows = 64 edges x {src,dst} = 128 rows, cols = 128.
// out = relu(concat(prev, te) @ W_self + b_self + neigh_proj[endpoint])
// K = 192: k<128 from feat rows (staged from global), k>=128 from te (LDS).
// In-place safe: each edge row is read (k-loop) then written (epilogue) only
// by its own block.
__global__ __launch_bounds__(256) void k_edge(const float* __restrict__ featS,
                                              const float* __restrict__ featD,
                                              float* __restrict__ outS,
                                              float* __restrict__ outD,
                                              const int* __restrict__ src,
                                              const int* __restrict__ dst,
                                              const float* __restrict__ ts,
                                              const float* __restrict__ W,
                                              const float* __restrict__ bias,
                                              const float* __restrict__ neigh,
                                              const float* __restrict__ omega,
                                              const float* __restrict__ phase) {
    __shared__ float Xs[16][132];    // [k][row(128)], stride 132 -> 2-way alias
    __shared__ float Ws[16][128];    // [k][col]
    __shared__ float te_s[64][68];   // [td][edge_local(64)]
    int tid = threadIdx.x;
    int e0 = blockIdx.x * 64;

    {   // time encoding for this block's 64 edges
        int tl = tid & 63;
        int j0 = (tid >> 6) * 16;
        float tval = ts[min(e0 + tl, EE - 1)];
#pragma unroll
        for (int j = 0; j < 16; ++j) {
            int jj = j0 + j;
            te_s[jj][tl] = cosf(fmaf(tval, omega[jj], phase[jj]));
        }
    }

    int tx = tid & 15, ty = tid >> 4;
    float acc[8][8];
#pragma unroll
    for (int i = 0; i < 8; ++i)
#pragma unroll
        for (int j = 0; j < 8; ++j) acc[i][j] = 0.f;
    __syncthreads();

    // Phase A: k = 0..127 (feat half)
    for (int ch = 0; ch < 8; ++ch) {
        int k0 = ch * 16;
        {   // stage W chunk
            int v = tid;
#pragma unroll
            for (int r = 0; r < 2; ++r, v += 256) {
                int kk = v >> 5, c4 = v & 31;
                *(float4*)&Ws[kk][c4 * 4] =
                    *(const float4*)(W + (size_t)(k0 + kk) * 128 + c4 * 4);
            }
        }
        {   // stage X chunk (transposed): 512 float4, 2 per thread
            int v = tid;
#pragma unroll
            for (int r = 0; r < 2; ++r, v += 256) {
                int row = v >> 2, q = v & 3;
                int e = (row < 64) ? (e0 + row) : (e0 + row - 64);
                const float* fp = (row < 64) ? featS : featD;
                e = min(e, EE - 1);
                float4 x = *(const float4*)(fp + (size_t)e * 128 + k0 + q * 4);
                Xs[q * 4 + 0][row] = x.x; Xs[q * 4 + 1][row] = x.y;
                Xs[q * 4 + 2][row] = x.z; Xs[q * 4 + 3][row] = x.w;
            }
        }
        __syncthreads();
#pragma unroll
        for (int kk = 0; kk < 16; ++kk) {
            float4 a0 = *(const float4*)&Xs[kk][4 * ty];
            float4 a1 = *(const float4*)&Xs[kk][64 + 4 * ty];
            float4 b0 = *(const float4*)&Ws[kk][4 * tx];
            float4 b1 = *(const float4*)&Ws[kk][64 + 4 * tx];
            float av[8] = {a0.x, a0.y, a0.z, a0.w, a1.x, a1.y, a1.z, a1.w};
            float bv[8] = {b0.x, b0.y, b0.z, b0.w, b1.x, b1.y, b1.z, b1.w};
#pragma unroll
            for (int i = 0; i < 8; ++i)
#pragma unroll
                for (int j = 0; j < 8; ++j)
                    acc[i][j] = fmaf(av[i], bv[j], acc[i][j]);
        }
        __syncthreads();
    }

    // Phase B: k = 128..191 (time-encoding half; A-fragment straight from te_s)
    for (int ch = 8; ch < 12; ++ch) {
        int k0 = ch * 16;
        {
            int v = tid;
#pragma unroll
            for (int r = 0; r < 2; ++r, v += 256) {
                int kk = v >> 5, c4 = v & 31;
                *(float4*)&Ws[kk][c4 * 4] =
                    *(const float4*)(W + (size_t)(k0 + kk) * 128 + c4 * 4);
            }
        }
        __syncthreads();
#pragma unroll
        for (int kk = 0; kk < 16; ++kk) {
            int kt = k0 - 128 + kk;
            float4 a0 = *(const float4*)&te_s[kt][4 * ty];
            float4 b0 = *(const float4*)&Ws[kk][4 * tx];
            float4 b1 = *(const float4*)&Ws[kk][64 + 4 * tx];
            float av[8] = {a0.x, a0.y, a0.z, a0.w, a0.x, a0.y, a0.z, a0.w};
            float bv[8] = {b0.x, b0.y, b0.z, b0.w, b1.x, b1.y, b1.z, b1.w};
#pragma unroll
            for (int i = 0; i < 8; ++i)
#pragma unroll
                for (int j = 0; j < 8; ++j)
                    acc[i][j] = fmaf(av[i], bv[j], acc[i][j]);
        }
        __syncthreads();
    }

    // Epilogue: + b_self + neigh_proj[endpoint], relu, store (in place).
    float4 bb0 = *(const float4*)(bias + 4 * tx);
    float4 bb1 = *(const float4*)(bias + 64 + 4 * tx);
#pragma unroll
    for (int i = 0; i < 8; ++i) {
        bool isS = (i < 4);
        int el = 4 * ty + (i & 3);
        int e = e0 + el;
        if (e < EE) {
            int node = isS ? src[e] : dst[e];
            const float* np = neigh + (size_t)node * 128;
            float4 n0v = *(const float4*)(np + 4 * tx);
            float4 n1v = *(const float4*)(np + 64 + 4 * tx);
            float* op = (isS ? outS : outD) + (size_t)e * 128;
            float4 r0, r1;
            r0.x = fmaxf(acc[i][0] + n0v.x + bb0.x, 0.f);
            r0.y = fmaxf(acc[i][1] + n0v.y + bb0.y, 0.f);
            r0.z = fmaxf(acc[i][2] + n0v.z + bb0.z, 0.f);
            r0.w = fmaxf(acc[i][3] + n0v.w + bb0.w, 0.f);
            r1.x = fmaxf(acc[i][4] + n1v.x + bb1.x, 0.f);
            r1.y = fmaxf(acc[i][5] + n1v.y + bb1.y, 0.f);
            r1.z = fmaxf(acc[i][6] + n1v.z + bb1.z, 0.f);
            r1.w = fmaxf(acc[i][7] + n1v.w + bb1.w, 0.f);
            *(float4*)(op + 4 * tx) = r0;
            *(float4*)(op + 64 + 4 * tx) = r1;
        }
    }
}

// ---------------------------------------------------------------------------
extern "C" void kernel_launch(void* const* d_in, const int* in_sizes, int n_in,
                              void* d_out, int out_size, void* d_ws, size_t ws_size,
                              hipStream_t stream) {
    const float* nfeat = (const float*)d_in[0];
    const float* efeat = (const float*)d_in[1];
    const int*   src   = (const int*)d_in[2];
    const int*   dst   = (const int*)d_in[3];
    const float* ts    = (const float*)d_in[4];
    const float* Wself[2]  = {(const float*)d_in[5],  (const float*)d_in[11]};
    const float* bself[2]  = {(const float*)d_in[6],  (const float*)d_in[12]};
    const float* Wneigh[2] = {(const float*)d_in[7],  (const float*)d_in[13]};
    const float* bneigh[2] = {(const float*)d_in[8],  (const float*)d_in[14]};
    const float* omega[2]  = {(const float*)d_in[9],  (const float*)d_in[15]};
    const float* phase[2]  = {(const float*)d_in[10], (const float*)d_in[16]};

    // d_out doubles as the edge-feature ping-pong storage (in-place layers).
    float* outS = (float*)d_out;                   // src_feat  [E,128]
    float* outD = outS + (size_t)EE * 128;         // dst_feat  [E,128]

    // workspace: mean | neigh | pos | eidx   (~128.4 MB)
    float* mean  = (float*)d_ws;
    float* neigh = mean + (size_t)NN * 128;
    int*   pos   = (int*)(neigh + (size_t)NN * 128);
    int*   eidx  = pos + NN;

    hipMemsetAsync(pos, 0, NN * sizeof(int), stream);
    k_build<<<(EE + 255) / 256, 256, 0, stream>>>(src, dst, pos, eidx);
    k_combine<<<(EE * 32) / 256, 256, 0, stream>>>(nfeat, efeat, src, dst, outS, outD);

    for (int l = 0; l < 2; ++l) {
        k_agg<<<(NN * 64 + 255) / 256, 256, 0, stream>>>(outS, outD, pos, eidx, mean);
        k_neigh<<<(NN + 63) / 64, 256, 0, stream>>>(mean, Wneigh[l], bneigh[l], neigh);
        k_edge<<<(EE + 63) / 64, 256, 0, stream>>>(outS, outD, outS, outD, src, dst, ts,
                                                   Wself[l], bself[l], neigh,
                                                   omega[l], phase[l]);
    }
}